// Round 9
// baseline (187.776 us; speedup 1.0000x reference)
//
#include <hip/hip_runtime.h>
#include <hip/hip_bf16.h>

// MEASUREMENT ROUND — kernels identical to R8, wrapped in idempotent rep
// loops (GEMM_REPS=6, SCAN_REPS=10) so each kernel's duration exceeds the
// harness's ~40us poison-fills and surfaces in rocprof top-5 WITH counters.
// Math/outputs unchanged (every rep recomputes the same values).
//
// Oja scan, reformulated. G[b][n][t] = row_n . x_t for n in [0,1088):
// rows 0..1023 = W0 rows, rows 1024..1087 = X rows (=> S = X X^T).
// Scan: exact projected Oja recurrence on u[j] = W_t . x_j:
//   y_t = sigmoid(u[t]);  u <- (1-lr*y^2)*u + (lr*y)*S[t,:]

#define BB 8
#define TT 64
#define NI 1024
#define NO 1024
#define NTOT 1088            // 1024 W rows + 64 X rows
#define NTILES 68            // NTOT/16
#define PADBF 1032           // LDS row stride in bf16 (1024 + 8)
#define GEMM_REPS 6
#define SCAN_REPS 10

typedef __attribute__((ext_vector_type(8))) short bf16x8;
typedef __attribute__((ext_vector_type(4))) float f32x4;

__device__ __forceinline__ short f2bf(float f) {
    __hip_bfloat16 h = __float2bfloat16(f);
    return __builtin_bit_cast(short, h);
}

// ---------- Kernel 0: X (f32) -> Xb16 (bf16), 524288 elements ----------
__global__ __launch_bounds__(256)
void xcvt_kernel(const float* __restrict__ X, ushort* __restrict__ Xb16)
{
    const int i = blockIdx.x * 256 + threadIdx.x;   // float4 index, 131072 total
    const float4 v = *reinterpret_cast<const float4*>(X + (size_t)i * 4);
    short4 s;
    s.x = f2bf(v.x); s.y = f2bf(v.y); s.z = f2bf(v.z); s.w = f2bf(v.w);
    *reinterpret_cast<short4*>(Xb16 + (size_t)i * 4) = s;
}

// ---------- Kernel 1: G[b][n][t] via MFMA, bf16 LDS A panel ----------
__global__ __launch_bounds__(256, 4)
void gemm_kernel(const float* __restrict__ X, const float* __restrict__ W0,
                 const ushort* __restrict__ Xb16, float* __restrict__ G)
{
    __shared__ ushort As[16 * PADBF];   // 33,024 B

    const int tid  = threadIdx.x;
    const int lane = tid & 63;
    const int wave = tid >> 6;
    const int b  = blockIdx.x & 7;
    const int nt = blockIdx.x >> 3;
    const int n0 = nt * 16;
    const int t0 = wave * 16;

    const int r  = lane & 15;
    const int kb = lane >> 4;

    const float* __restrict__ Abase =
        (n0 < NO) ? (W0 + ((size_t)b * NO + n0) * NI)
                  : (X + ((size_t)b * TT + (n0 - NO)) * NI);
    const ushort* __restrict__ Bbase =
        Xb16 + ((size_t)b * TT + t0 + r) * NI + kb * 8;
    const ushort* __restrict__ Ap = &As[r * PADBF + kb * 8];

    const int tcol = lane & 15;
    const int mrow = (lane >> 4) * 4;

#pragma unroll 1
    for (int rep = 0; rep < GEMM_REPS; ++rep) {
        // ---- stage: burst-load 16 rows, then cvt+ds_write burst ----
        float4 v[16];
#pragma unroll
        for (int j = 0; j < 16; ++j)
            v[j] = *reinterpret_cast<const float4*>(Abase + (size_t)j * NI + tid * 4);
#pragma unroll
        for (int j = 0; j < 16; ++j) {
            short4 s;
            s.x = f2bf(v[j].x); s.y = f2bf(v[j].y); s.z = f2bf(v[j].z); s.w = f2bf(v[j].w);
            *reinterpret_cast<short4*>(&As[j * PADBF + tid * 4]) = s;
        }
        __syncthreads();

        // ---- MFMA loop: ds_read_b128 + 16B global B + MFMA ----
        f32x4 acc = {0.f, 0.f, 0.f, 0.f};
#pragma unroll 8
        for (int kk = 0; kk < 32; ++kk) {
            const bf16x8 a  = *reinterpret_cast<const bf16x8*>(Ap + kk * 32);
            const bf16x8 bv = *reinterpret_cast<const bf16x8*>(Bbase + kk * 32);
            acc = __builtin_amdgcn_mfma_f32_16x16x32_bf16(a, bv, acc, 0, 0, 0);
        }

#pragma unroll
        for (int rr = 0; rr < 4; ++rr)
            G[((size_t)b * NTOT + n0 + mrow + rr) * TT + t0 + tcol] = acc[rr];

        __syncthreads();   // protect As before next rep's restage
    }
}

// ---------- Kernel 2: projected-Oja scan, 2 rows per wave ----------
__global__ __launch_bounds__(512, 4)
void scan_kernel(const float* __restrict__ G, float* __restrict__ out)
{
    __shared__ float Sl[TT][TT];        // 16 KB: S[b]
    __shared__ float ybuf[16][TT + 1];

    const int tid  = threadIdx.x;
    const int lane = tid & 63;
    const int wave = tid >> 6;
    const int b  = blockIdx.x & 7;
    const int o0 = (blockIdx.x >> 3) * 16;

#pragma unroll 1
    for (int rep = 0; rep < SCAN_REPS; ++rep) {
        __syncthreads();   // protect Sl/ybuf from previous rep's readers

        // stage S[b] = G rows 1024..1087 (4096 contiguous floats)
        {
            const float4* __restrict__ src =
                reinterpret_cast<const float4*>(G + ((size_t)b * NTOT + NO) * TT);
            float4* dst = reinterpret_cast<float4*>(&Sl[0][0]);
            dst[tid]       = src[tid];
            dst[tid + 512] = src[tid + 512];
        }

        const int r0 = o0 + wave * 2;
        float u0 = G[((size_t)b * NTOT + r0) * TT + lane];
        float u1 = G[((size_t)b * NTOT + r0 + 1) * TT + lane];

        __syncthreads();

        const float lr = 1.0f / 1024.0f;
        const float L2E = 1.44269504f;
        float y0s = 0.0f, y1s = 0.0f;
        float srow = Sl[0][lane];
#pragma unroll
        for (int t = 0; t < TT; ++t) {
            const float srow_next = (t + 1 < TT) ? Sl[t + 1][lane] : 0.0f;
            const float sg0 = __int_as_float(__builtin_amdgcn_readlane(__float_as_int(u0), t));
            const float sg1 = __int_as_float(__builtin_amdgcn_readlane(__float_as_int(u1), t));
            const float e0 = __builtin_amdgcn_exp2f(sg0 * -L2E);
            const float e1 = __builtin_amdgcn_exp2f(sg1 * -L2E);
            const float y0 = __builtin_amdgcn_rcpf(1.0f + e0);
            const float y1 = __builtin_amdgcn_rcpf(1.0f + e1);
            y0s = (lane == t) ? y0 : y0s;
            y1s = (lane == t) ? y1 : y1s;
            const float c20 = lr * y0, c21 = lr * y1;
            const float c10 = fmaf(-c20, y0, 1.0f);
            const float c11 = fmaf(-c21, y1, 1.0f);
            u0 = fmaf(c10, u0, c20 * srow);
            u1 = fmaf(c11, u1, c21 * srow);
            srow = srow_next;
        }

        ybuf[wave * 2][lane]     = y0s;
        ybuf[wave * 2 + 1][lane] = y1s;
        __syncthreads();

        const int oo = tid & 15;
        const int t2 = tid >> 4;
#pragma unroll
        for (int q = 0; q < 2; ++q) {
            const int t = t2 * 2 + q;
            out[(size_t)b * TT * NO + (size_t)t * NO + o0 + oo] = ybuf[oo][t];
        }
    }
}

extern "C" void kernel_launch(void* const* d_in, const int* in_sizes, int n_in,
                              void* d_out, int out_size, void* d_ws, size_t ws_size,
                              hipStream_t stream) {
    const float* X  = (const float*)d_in[0];   // [8][64][1024]
    const float* W0 = (const float*)d_in[1];   // [8][1024][1024]
    float* out = (float*)d_out;                // [8][64][1024]

    float*  G    = (float*)d_ws;                          // [8][1088][64] = 2,228,224 B
    ushort* Xb16 = (ushort*)((char*)d_ws + 2228224);      // [8][64][1024] bf16 = 1 MB

    xcvt_kernel<<<512, 256, 0, stream>>>(X, Xb16);
    gemm_kernel<<<BB * NTILES, 256, 0, stream>>>(X, W0, Xb16, G);
    scan_kernel<<<512, 512, 0, stream>>>(G, out);
}

// Round 10
// 33.525 us; speedup vs baseline: 5.6012x; 5.6012x over previous
//
#include <hip/hip_runtime.h>
#include <hip/hip_bf16.h>

// Oja scan, reformulated. G[b][n][t] = row_n . x_t for n in [0,1088):
// rows 0..1023 = W0 rows, rows 1024..1087 = X rows (=> S = X X^T).
// Scan: exact projected Oja recurrence on u[j] = W_t . x_j:
//   y_t = sigmoid(u[t]);  u <- (1-lr*y^2)*u + (lr*y)*S[t,:]
// R10: scan re-layout for lane-parallel sigmoid. Lane = (row r=lane&3,
// jblock jb=lane>>2); lane holds u[r][jb*4..+3] in 4 statically-indexed
// VGPRs. Per step: 1 ds_bpermute (fetch u[r][t] from owning lane),
// 1 exp2 + 1 rcp covering 4 rows, 1 ds_read_b128 of S[t][jb*4..+3],
// 8 FMA update. Gemm/xcvt byte-identical to R8 (single variable).

#define BB 8
#define TT 64
#define NI 1024
#define NO 1024
#define NTOT 1088            // 1024 W rows + 64 X rows
#define NTILES 68            // NTOT/16
#define PADBF 1032           // LDS row stride in bf16 (1024 + 8)

typedef __attribute__((ext_vector_type(8))) short bf16x8;
typedef __attribute__((ext_vector_type(4))) float f32x4;

__device__ __forceinline__ short f2bf(float f) {
    __hip_bfloat16 h = __float2bfloat16(f);
    return __builtin_bit_cast(short, h);
}

// ---------- Kernel 0: X (f32) -> Xb16 (bf16), 524288 elements ----------
__global__ __launch_bounds__(256)
void xcvt_kernel(const float* __restrict__ X, ushort* __restrict__ Xb16)
{
    const int i = blockIdx.x * 256 + threadIdx.x;   // float4 index, 131072 total
    const float4 v = *reinterpret_cast<const float4*>(X + (size_t)i * 4);
    short4 s;
    s.x = f2bf(v.x); s.y = f2bf(v.y); s.z = f2bf(v.z); s.w = f2bf(v.w);
    *reinterpret_cast<short4*>(Xb16 + (size_t)i * 4) = s;
}

// ---------- Kernel 1: G[b][n][t] via MFMA, bf16 LDS A panel ----------
__global__ __launch_bounds__(256, 4)
void gemm_kernel(const float* __restrict__ X, const float* __restrict__ W0,
                 const ushort* __restrict__ Xb16, float* __restrict__ G)
{
    __shared__ ushort As[16 * PADBF];   // 33,024 B

    const int tid  = threadIdx.x;
    const int lane = tid & 63;
    const int wave = tid >> 6;
    const int b  = blockIdx.x & 7;       // blockIdx%8 = batch -> XCD-local X
    const int nt = blockIdx.x >> 3;
    const int n0 = nt * 16;
    const int t0 = wave * 16;

    const int r  = lane & 15;
    const int kb = lane >> 4;

    const float* __restrict__ Abase =
        (n0 < NO) ? (W0 + ((size_t)b * NO + n0) * NI)
                  : (X + ((size_t)b * TT + (n0 - NO)) * NI);

    // ---- stage: burst-load 16 rows, then cvt+ds_write burst ----
    float4 v[16];
#pragma unroll
    for (int j = 0; j < 16; ++j)
        v[j] = *reinterpret_cast<const float4*>(Abase + (size_t)j * NI + tid * 4);
#pragma unroll
    for (int j = 0; j < 16; ++j) {
        short4 s;
        s.x = f2bf(v[j].x); s.y = f2bf(v[j].y); s.z = f2bf(v[j].z); s.w = f2bf(v[j].w);
        *reinterpret_cast<short4*>(&As[j * PADBF + tid * 4]) = s;
    }
    __syncthreads();

    // ---- MFMA loop: pure ds_read_b128 + 16B global B + MFMA ----
    const ushort* __restrict__ Bbase =
        Xb16 + ((size_t)b * TT + t0 + r) * NI + kb * 8;
    const ushort* __restrict__ Ap = &As[r * PADBF + kb * 8];

    f32x4 acc = {0.f, 0.f, 0.f, 0.f};
#pragma unroll 8
    for (int kk = 0; kk < 32; ++kk) {
        const bf16x8 a  = *reinterpret_cast<const bf16x8*>(Ap + kk * 32);
        const bf16x8 bv = *reinterpret_cast<const bf16x8*>(Bbase + kk * 32);
        acc = __builtin_amdgcn_mfma_f32_16x16x32_bf16(a, bv, acc, 0, 0, 0);
    }

    // D layout: col t = lane&15, row n = (lane>>4)*4 + rr   [m89-verified]
    const int tcol = lane & 15;
    const int mrow = (lane >> 4) * 4;
#pragma unroll
    for (int rr = 0; rr < 4; ++rr)
        G[((size_t)b * NTOT + n0 + mrow + rr) * TT + t0 + tcol] = acc[rr];
}

// ---------- Kernel 2: lane-parallel projected-Oja scan ----------
// 512 blocks x 256 thr (4 waves). Block: batch b = bid&7, 16 o-rows.
// Wave: 4 rows. Lane l: r = l&3 (row), jb = l>>2 (j-block of 4).
__global__ __launch_bounds__(256, 8)
void scan_kernel(const float* __restrict__ G, float* __restrict__ out)
{
    __shared__ float Sl[TT][TT];      // 16 KB: S[b]
    __shared__ float ybuf[16][68];    // row-local y trajectories (padded)

    const int tid  = threadIdx.x;
    const int lane = tid & 63;
    const int wave = tid >> 6;
    const int b  = blockIdx.x & 7;     // XCD-aligned with gemm's G[b] writes
    const int o0 = (blockIdx.x >> 3) * 16;

    // stage S[b] = G rows 1024..1087 (4096 floats; 4 float4 per thread)
    {
        const float4* __restrict__ src =
            reinterpret_cast<const float4*>(G + ((size_t)b * NTOT + NO) * TT);
        float4* dst = reinterpret_cast<float4*>(&Sl[0][0]);
#pragma unroll
        for (int q = 0; q < 4; ++q)
            dst[tid + q * 256] = src[tid + q * 256];
    }

    const int r  = lane & 3;           // row within wave's group of 4
    const int jb = lane >> 2;          // j-block 0..15
    const int row = o0 + wave * 4 + r; // global o

    // u[r][jb*4..+3] (contiguous float4 from G row)
    const float4 uu = *reinterpret_cast<const float4*>(
        G + ((size_t)b * NTOT + row) * TT + jb * 4);
    float u0 = uu.x, u1 = uu.y, u2 = uu.z, u3 = uu.w;

    __syncthreads();

    const float lr   = 1.0f / 1024.0f;
    const float nL2E = -1.44269504f;   // -log2(e)
    float y0 = 0.f, y1 = 0.f, y2 = 0.f, y3 = 0.f;

#pragma unroll
    for (int t = 0; t < TT; ++t) {
        // fetch u[r][t] from owning lane (jb = t>>2), slot t&3 (compile-time)
        const int srcl = (t & 0x3C) | r;
        const float uv = ((t & 3) == 0) ? u0 : ((t & 3) == 1) ? u1
                       : ((t & 3) == 2) ? u2 : u3;
        const float pre = __shfl(uv, srcl, 64);

        const float e = __builtin_amdgcn_exp2f(pre * nL2E);  // exp(-pre)
        const float y = __builtin_amdgcn_rcpf(1.0f + e);

        const bool own = (jb == (t >> 2));
        if ((t & 3) == 0) y0 = own ? y : y0;
        if ((t & 3) == 1) y1 = own ? y : y1;
        if ((t & 3) == 2) y2 = own ? y : y2;
        if ((t & 3) == 3) y3 = own ? y : y3;

        const float c2 = lr * y;
        const float c1 = fmaf(-c2, y, 1.0f);   // 1 - lr*y^2

        const float4 s = *reinterpret_cast<const float4*>(&Sl[t][jb * 4]);
        u0 = fmaf(c1, u0, c2 * s.x);
        u1 = fmaf(c1, u1, c2 * s.y);
        u2 = fmaf(c1, u2, c2 * s.z);
        u3 = fmaf(c1, u3, c2 * s.w);
    }

    // lane holds y[row][t] for t = jb*4..+3 -> LDS, then coalesced store
    {
        float4 yv; yv.x = y0; yv.y = y1; yv.z = y2; yv.w = y3;
        *reinterpret_cast<float4*>(&ybuf[wave * 4 + r][jb * 4]) = yv;
    }
    __syncthreads();

    // out[b][t][o0 + g*4 .. +3]: thread tid -> t = tid>>2, g = tid&3
    {
        const int t = tid >> 2;
        const int g = tid & 3;
        float4 ov;
        ov.x = ybuf[g * 4 + 0][t];
        ov.y = ybuf[g * 4 + 1][t];
        ov.z = ybuf[g * 4 + 2][t];
        ov.w = ybuf[g * 4 + 3][t];
        *reinterpret_cast<float4*>(
            &out[(size_t)b * TT * NO + (size_t)t * NO + o0 + g * 4]) = ov;
    }
}

extern "C" void kernel_launch(void* const* d_in, const int* in_sizes, int n_in,
                              void* d_out, int out_size, void* d_ws, size_t ws_size,
                              hipStream_t stream) {
    const float* X  = (const float*)d_in[0];   // [8][64][1024]
    const float* W0 = (const float*)d_in[1];   // [8][1024][1024]
    float* out = (float*)d_out;                // [8][64][1024]

    float*  G    = (float*)d_ws;                          // [8][1088][64] = 2,228,224 B
    ushort* Xb16 = (ushort*)((char*)d_ws + 2228224);      // [8][64][1024] bf16 = 1 MB

    xcvt_kernel<<<512, 256, 0, stream>>>(X, Xb16);
    gemm_kernel<<<BB * NTILES, 256, 0, stream>>>(X, W0, Xb16, G);
    scan_kernel<<<512, 256, 0, stream>>>(G, out);
}